// Round 3
// baseline (750.483 us; speedup 1.0000x reference)
//
#include <hip/hip_runtime.h>
#include <hip/hip_bf16.h>
#include <cstdint>

typedef unsigned short u16;
typedef __attribute__((ext_vector_type(8))) short bf16x8;
typedef __attribute__((ext_vector_type(4))) float f32x4;

#define BATCH 4
#define CDIM 256
#define NTOK 4096   // H*W

__device__ inline u16 f2bf(float f) {
  union { float f; uint32_t u; } un; un.f = f;
  uint32_t u = un.u;
  u += 0x7fffu + ((u >> 16) & 1u);
  return (u16)(u >> 16);
}
__device__ inline float bf2f(u16 h) {
  union { uint32_t u; float f; } un; un.u = ((uint32_t)h) << 16; return un.f;
}

// ---------------------------------------------------------------------------
// LayerNorm: x [B, C, N] -> xn bf16 [B*N, C]
// ---------------------------------------------------------------------------
__global__ __launch_bounds__(256) void ln_kernel(const float* __restrict__ x,
                                                 const float* __restrict__ gamma,
                                                 const float* __restrict__ beta,
                                                 u16* __restrict__ xn) {
  __shared__ float tile[CDIM][33];
  __shared__ float reds[8][32];
  __shared__ float reds2[8][32];
  __shared__ float mu_s[32], rs_s[32];

  int b  = blockIdx.x >> 7;
  int n0 = (blockIdx.x & 127) * 32;
  const float* xb = x + (size_t)b * CDIM * NTOK;

  int t = threadIdx.x & 31;
  int g = threadIdx.x >> 5;

  for (int c = g; c < CDIM; c += 8)
    tile[c][t] = xb[(size_t)c * NTOK + n0 + t];
  __syncthreads();

  float s = 0.f, s2 = 0.f;
  for (int c = g * 32; c < g * 32 + 32; ++c) {
    float v = tile[c][t];
    s += v; s2 += v * v;
  }
  reds[g][t] = s; reds2[g][t] = s2;
  __syncthreads();
  if (threadIdx.x < 32) {
    float ts = 0.f, ts2 = 0.f;
    for (int gg = 0; gg < 8; ++gg) { ts += reds[gg][threadIdx.x]; ts2 += reds2[gg][threadIdx.x]; }
    float mu = ts / CDIM;
    float var = ts2 / CDIM - mu * mu;
    mu_s[threadIdx.x] = mu;
    rs_s[threadIdx.x] = rsqrtf(var + 1e-5f);
  }
  __syncthreads();

  int c = threadIdx.x;
  float gam = gamma[c], bet = beta[c];
  u16* out = xn + ((size_t)b * NTOK + n0) * CDIM;
  for (int tt = 0; tt < 32; ++tt) {
    float v = tile[c][tt];
    float y = (v - mu_s[tt]) * rs_s[tt] * gam + bet;
    out[(size_t)tt * CDIM + c] = f2bf(y);
  }
}

// ---------------------------------------------------------------------------
// W [K, Cout] fp32 -> WT bf16 [Cout, K]
// ---------------------------------------------------------------------------
__global__ __launch_bounds__(256) void wt_kernel(const float* __restrict__ W,
                                                 u16* __restrict__ WT) {
  __shared__ float tile[32][33];
  int i0 = blockIdx.y * 32;
  int j0 = blockIdx.x * 32;
  int tx = threadIdx.x, ty = threadIdx.y;
  for (int r = ty; r < 32; r += 8)
    tile[r][tx] = W[(size_t)(i0 + r) * CDIM + j0 + tx];
  __syncthreads();
  for (int r = ty; r < 32; r += 8)
    WT[(size_t)(j0 + r) * CDIM + i0 + tx] = f2bf(tile[tx][r]);
}

// ---------------------------------------------------------------------------
// bf16 MFMA GEMM (projections): C = A[M,K] * B[Nt,K]^T
// MODE 0: bf16 row-major; MODE 1: bf16 transposed C[n*M+m]
// ---------------------------------------------------------------------------
template <int BM, int BN, int MODE>
__global__ __launch_bounds__(256) void gemm_bt(const u16* __restrict__ Ag,
                                               const u16* __restrict__ Bg,
                                               void* __restrict__ Cg,
                                               int M, int Nt, int K,
                                               size_t sA_, size_t sB_, size_t sC_) {
  constexpr int BK = 32;
  constexpr int TM = BM / 32;
  constexpr int TN = BN / 32;
  __shared__ u16 shA[BM][BK + 8];
  __shared__ u16 shB[BN][BK + 8];

  int bz = blockIdx.z;
  const u16* A = Ag + (size_t)bz * sA_;
  const u16* B = Bg + (size_t)bz * sB_;

  int m0 = blockIdx.y * BM;
  int n0 = blockIdx.x * BN;

  int tid  = threadIdx.x;
  int lane = tid & 63;
  int wave = tid >> 6;
  int wm = wave >> 1, wn = wave & 1;
  int col  = lane & 15;
  int quad = lane >> 4;

  f32x4 acc[TM][TN];
#pragma unroll
  for (int i = 0; i < TM; ++i)
#pragma unroll
    for (int j = 0; j < TN; ++j) acc[i][j] = (f32x4){0.f, 0.f, 0.f, 0.f};

  constexpr int ACH = BM * BK / 8;
  constexpr int BCH = BN * BK / 8;

  for (int kb = 0; kb < K; kb += BK) {
    __syncthreads();
#pragma unroll
    for (int c = tid; c < ACH; c += 256) {
      int row = c >> 2, kc = c & 3;
      *(uint4*)&shA[row][kc * 8] = *(const uint4*)&A[(size_t)(m0 + row) * K + kb + kc * 8];
    }
#pragma unroll
    for (int c = tid; c < BCH; c += 256) {
      int row = c >> 2, kc = c & 3;
      *(uint4*)&shB[row][kc * 8] = *(const uint4*)&B[(size_t)(n0 + row) * K + kb + kc * 8];
    }
    __syncthreads();

    bf16x8 af[TM], bfv[TN];
#pragma unroll
    for (int i = 0; i < TM; ++i)
      af[i] = *(const bf16x8*)&shA[wm * (BM / 2) + i * 16 + col][quad * 8];
#pragma unroll
    for (int j = 0; j < TN; ++j)
      bfv[j] = *(const bf16x8*)&shB[wn * (BN / 2) + j * 16 + col][quad * 8];
#pragma unroll
    for (int i = 0; i < TM; ++i)
#pragma unroll
      for (int j = 0; j < TN; ++j)
        acc[i][j] = __builtin_amdgcn_mfma_f32_16x16x32_bf16(af[i], bfv[j], acc[i][j], 0, 0, 0);
  }

  int r0 = quad * 4;
#pragma unroll
  for (int i = 0; i < TM; ++i) {
    int mbase = m0 + wm * (BM / 2) + i * 16 + r0;
#pragma unroll
    for (int j = 0; j < TN; ++j) {
      int n = n0 + wn * (BN / 2) + j * 16 + col;
#pragma unroll
      for (int r = 0; r < 4; ++r) {
        int m = mbase + r;
        float v = acc[i][j][r];
        if (MODE == 0) {
          ((u16*)Cg)[(size_t)bz * sC_ + (size_t)m * Nt + n] = f2bf(v);
        } else {
          ((u16*)Cg)[(size_t)bz * sC_ + (size_t)n * M + m] = f2bf(v);
        }
      }
    }
  }
}

// ---------------------------------------------------------------------------
// Fused flash attention, wave-owns-rows layout.
// Block: 256 thr = 4 waves; wave w owns Q rows [w*16, w*16+16) of a 64-row
// Q tile. Per KV tile (64): S = Q K^T (wave computes 16x64), softmax stats
// m/l register-resident (shuffle over 16-lane col groups), P1/P2 in per-wave
// private LDS, PV accumulates O1 (softmax path) + O2 (relu^2 path) over all
// 256 C columns. K/V double-buffered: next tile's global loads issued before
// compute, ds_write after PV, 2 barriers/tile.
// ---------------------------------------------------------------------------
#define KLD 264   // u16 stride, K tile rows (256+8)
#define VLD 72    // u16 stride, V^T tile rows (64+8)
#define PLD 72

__global__ __launch_bounds__(256, 1) void fa_kernel(const u16* __restrict__ Qg,
                                                    const u16* __restrict__ Kg,
                                                    const u16* __restrict__ Vtg,
                                                    const u16* __restrict__ xng,
                                                    const float* __restrict__ w1p,
                                                    const float* __restrict__ w2p,
                                                    float* __restrict__ outg) {
  // K0 33792 | K1 33792 | V0 36864 | V1 36864 | P 18432  = 159744 B
  __shared__ __align__(16) char smem[159744];
  u16* Kb0 = (u16*)smem;
  u16* Kb1 = (u16*)(smem + 33792);
  u16* Vb0 = (u16*)(smem + 67584);
  u16* Vb1 = (u16*)(smem + 104448);
  u16* Pb  = (u16*)(smem + 141312);
  float* otile = (float*)smem;          // epilogue overlay [256][68]

  int b  = blockIdx.x & 3;              // XCD swizzle: same XCD -> same batch
  int q0 = (blockIdx.x >> 2) * 64;

  const u16* Q  = Qg  + (size_t)b * NTOK * CDIM;
  const u16* K  = Kg  + (size_t)b * NTOK * CDIM;
  const u16* Vt = Vtg + (size_t)b * NTOK * CDIM;

  int tid  = threadIdx.x;
  int lane = tid & 63;
  int wave = tid >> 6;
  int col = lane & 15, quad = lane >> 4;

  u16* P1 = Pb + wave * 2304;           // per-wave [16][72]
  u16* P2 = P1 + 1152;

  // ---- stage KV tile 0 into buffer 0 ----
#pragma unroll
  for (int it = 0; it < 8; ++it) {
    int c = tid + it * 256;
    int row = c >> 5, ch = c & 31;
    *(uint4*)&Kb0[(size_t)row * KLD + ch * 8] = *(const uint4*)&K[(size_t)row * CDIM + ch * 8];
  }
#pragma unroll
  for (int it = 0; it < 8; ++it) {
    int c = tid + it * 256;
    int row = c >> 3, ch = c & 7;
    *(uint4*)&Vb0[(size_t)row * VLD + ch * 8] = *(const uint4*)&Vt[(size_t)row * NTOK + ch * 8];
  }

  // ---- Q A-frags straight from global (16B contiguous per frag) ----
  bf16x8 aq[8];
#pragma unroll
  for (int kk = 0; kk < 8; ++kk)
    aq[kk] = *(const bf16x8*)&Q[(size_t)(q0 + wave * 16 + col) * CDIM + kk * 32 + quad * 8];

  f32x4 o1[16], o2[16];
#pragma unroll
  for (int j = 0; j < 16; ++j) {
    o1[j] = (f32x4){0.f, 0.f, 0.f, 0.f};
    o2[j] = (f32x4){0.f, 0.f, 0.f, 0.f};
  }
  float mr[4], lr[4];
#pragma unroll
  for (int r = 0; r < 4; ++r) { mr[r] = -1e30f; lr[r] = 0.f; }

  __syncthreads();

  for (int t = 0; t < 64; ++t) {
    const u16* Ks = (t & 1) ? Kb1 : Kb0;
    const u16* Vs = (t & 1) ? Vb1 : Vb0;

    // ---- issue next tile's global loads (in flight during compute) ----
    uint4 gk[8], gv[8];
    if (t < 63) {
      int n1 = (t + 1) * 64;
#pragma unroll
      for (int it = 0; it < 8; ++it) {
        int c = tid + it * 256;
        int row = c >> 5, ch = c & 31;
        gk[it] = *(const uint4*)&K[(size_t)(n1 + row) * CDIM + ch * 8];
      }
#pragma unroll
      for (int it = 0; it < 8; ++it) {
        int c = tid + it * 256;
        int row = c >> 3, ch = c & 7;
        gv[it] = *(const uint4*)&Vt[(size_t)row * NTOK + n1 + ch * 8];
      }
    }

    // ---- S = Q K^T : wave computes its 16 rows x 64 cols ----
    f32x4 sacc[4];
#pragma unroll
    for (int j = 0; j < 4; ++j) sacc[j] = (f32x4){0.f, 0.f, 0.f, 0.f};
#pragma unroll
    for (int kk = 0; kk < 8; ++kk) {
#pragma unroll
      for (int j = 0; j < 4; ++j) {
        bf16x8 bk = *(const bf16x8*)&Ks[(size_t)(j * 16 + col) * KLD + kk * 32 + quad * 8];
        sacc[j] = __builtin_amdgcn_mfma_f32_16x16x32_bf16(aq[kk], bk, sacc[j], 0, 0, 0);
      }
    }

    // ---- row stats in registers (rows = quad*4+r, reduce over col group) ----
    float pm[4];
#pragma unroll
    for (int r = 0; r < 4; ++r) {
      float v = fmaxf(fmaxf(sacc[0][r], sacc[1][r]), fmaxf(sacc[2][r], sacc[3][r]));
      pm[r] = v;
    }
#pragma unroll
    for (int off = 1; off < 16; off <<= 1)
#pragma unroll
      for (int r = 0; r < 4; ++r) pm[r] = fmaxf(pm[r], __shfl_xor(pm[r], off));

    float mnew[4], alpha[4], rs[4];
#pragma unroll
    for (int r = 0; r < 4; ++r) {
      mnew[r] = fmaxf(mr[r], pm[r]);
      alpha[r] = __expf(mr[r] - mnew[r]);
      rs[r] = 0.f;
    }

    // ---- P1 = exp(S - m), P2 = relu(S)^2 -> per-wave LDS ----
#pragma unroll
    for (int j = 0; j < 4; ++j)
#pragma unroll
      for (int r = 0; r < 4; ++r) {
        float sv = sacc[j][r];
        float p1 = __expf(sv - mnew[r]);
        rs[r] += p1;
        float p2 = sv > 0.f ? sv * sv : 0.f;
        P1[(size_t)(quad * 4 + r) * PLD + j * 16 + col] = f2bf(p1);
        P2[(size_t)(quad * 4 + r) * PLD + j * 16 + col] = f2bf(p2);
      }
#pragma unroll
    for (int off = 1; off < 16; off <<= 1)
#pragma unroll
      for (int r = 0; r < 4; ++r) rs[r] += __shfl_xor(rs[r], off);
#pragma unroll
    for (int r = 0; r < 4; ++r) {
      lr[r] = lr[r] * alpha[r] + rs[r];
      mr[r] = mnew[r];
    }
    // rescale O1 by alpha
#pragma unroll
    for (int j = 0; j < 16; ++j)
#pragma unroll
      for (int r = 0; r < 4; ++r) o1[j][r] *= alpha[r];

    __syncthreads();   // P writes ordered before reads (and wave alignment)

    // ---- O1 += P1 V, O2 += P2 V over all 256 C columns ----
#pragma unroll
    for (int kk = 0; kk < 2; ++kk) {
      bf16x8 pa1 = *(const bf16x8*)&P1[(size_t)col * PLD + kk * 32 + quad * 8];
      bf16x8 pa2 = *(const bf16x8*)&P2[(size_t)col * PLD + kk * 32 + quad * 8];
#pragma unroll
      for (int j = 0; j < 16; ++j) {
        bf16x8 bv = *(const bf16x8*)&Vs[(size_t)(j * 16 + col) * VLD + kk * 32 + quad * 8];
        o1[j] = __builtin_amdgcn_mfma_f32_16x16x32_bf16(pa1, bv, o1[j], 0, 0, 0);
        o2[j] = __builtin_amdgcn_mfma_f32_16x16x32_bf16(pa2, bv, o2[j], 0, 0, 0);
      }
    }

    // ---- write next tile into the inactive buffer ----
    if (t < 63) {
      u16* Kn = (t & 1) ? Kb0 : Kb1;
      u16* Vn = (t & 1) ? Vb0 : Vb1;
#pragma unroll
      for (int it = 0; it < 8; ++it) {
        int c = tid + it * 256;
        int row = c >> 5, ch = c & 31;
        *(uint4*)&Kn[(size_t)row * KLD + ch * 8] = gk[it];
      }
#pragma unroll
      for (int it = 0; it < 8; ++it) {
        int c = tid + it * 256;
        int row = c >> 3, ch = c & 7;
        *(uint4*)&Vn[(size_t)row * VLD + ch * 8] = gv[it];
      }
    }
    __syncthreads();   // buffer handoff
  }

  // ---- epilogue: combine, residual, transpose to [c][n] ----
  float e1 = __expf(w1p[0]), e2 = __expf(w2p[0]);
  float a1 = e1 / (e1 + e2), a2 = e2 / (e1 + e2);
  float linv[4];
#pragma unroll
  for (int r = 0; r < 4; ++r) linv[r] = a1 / lr[r];

#pragma unroll
  for (int j = 0; j < 16; ++j)
#pragma unroll
    for (int r = 0; r < 4; ++r) {
      int row = wave * 16 + quad * 4 + r;   // local n
      int c   = j * 16 + col;
      float v = o1[j][r] * linv[r] + a2 * o2[j][r];
      v += bf2f(xng[((size_t)b * NTOK + q0 + row) * CDIM + c]);
      otile[(size_t)c * 68 + row] = v;
    }
  __syncthreads();

#pragma unroll
  for (int it = 0; it < 16; ++it) {
    int c  = it * 16 + (tid >> 4);
    int ch = tid & 15;
    *(float4*)&outg[((size_t)b * CDIM + c) * NTOK + q0 + ch * 4] =
        *(const float4*)&otile[(size_t)c * 68 + ch * 4];
  }
}

// ---------------------------------------------------------------------------
extern "C" void kernel_launch(void* const* d_in, const int* in_sizes, int n_in,
                              void* d_out, int out_size, void* d_ws, size_t ws_size,
                              hipStream_t stream) {
  const float* x     = (const float*)d_in[0];
  const float* gamma = (const float*)d_in[1];
  const float* beta  = (const float*)d_in[2];
  const float* Wq    = (const float*)d_in[3];
  const float* Wk    = (const float*)d_in[4];
  const float* Wv    = (const float*)d_in[5];
  const float* w1    = (const float*)d_in[6];
  const float* w2    = (const float*)d_in[7];
  float* out = (float*)d_out;

  char* ws = (char*)d_ws;
  size_t off = 0;
  u16* xn  = (u16*)(ws + off); off += (size_t)BATCH * NTOK * CDIM * 2;
  u16* WqT = (u16*)(ws + off); off += (size_t)CDIM * CDIM * 2;
  u16* WkT = (u16*)(ws + off); off += (size_t)CDIM * CDIM * 2;
  u16* WvT = (u16*)(ws + off); off += (size_t)CDIM * CDIM * 2;
  u16* Qb  = (u16*)(ws + off); off += (size_t)BATCH * NTOK * CDIM * 2;
  u16* Kb  = (u16*)(ws + off); off += (size_t)BATCH * NTOK * CDIM * 2;
  u16* VT  = (u16*)(ws + off); off += (size_t)BATCH * NTOK * CDIM * 2;  // [b][c][n]

  // 1) LayerNorm -> xn bf16 [B*N, C]
  ln_kernel<<<dim3(BATCH * (NTOK / 32)), 256, 0, stream>>>(x, gamma, beta, xn);

  // 2) weight transposes
  wt_kernel<<<dim3(8, 8), dim3(32, 8), 0, stream>>>(Wq, WqT);
  wt_kernel<<<dim3(8, 8), dim3(32, 8), 0, stream>>>(Wk, WkT);
  wt_kernel<<<dim3(8, 8), dim3(32, 8), 0, stream>>>(Wv, WvT);

  // 3) projections
  gemm_bt<128, 64, 0><<<dim3(4, 128, 1), 256, 0, stream>>>(
      xn, WqT, Qb, BATCH * NTOK, CDIM, CDIM, 0, 0, 0);
  gemm_bt<128, 64, 0><<<dim3(4, 128, 1), 256, 0, stream>>>(
      xn, WkT, Kb, BATCH * NTOK, CDIM, CDIM, 0, 0, 0);
  gemm_bt<128, 64, 1><<<dim3(4, 32, BATCH), 256, 0, stream>>>(
      xn, WvT, VT, NTOK, CDIM, CDIM,
      (size_t)NTOK * CDIM, 0, (size_t)NTOK * CDIM);

  // 4) fused attention + mix + residual + transpose
  fa_kernel<<<dim3(256), 256, 0, stream>>>(Qb, Kb, VT, xn, w1, w2, out);
}

// Round 4
// 373.356 us; speedup vs baseline: 2.0101x; 2.0101x over previous
//
#include <hip/hip_runtime.h>
#include <hip/hip_bf16.h>
#include <cstdint>

typedef unsigned short u16;
typedef __attribute__((ext_vector_type(8))) short bf16x8;
typedef __attribute__((ext_vector_type(4))) float f32x4;

#define BATCH 4
#define CDIM 256
#define NTOK 4096   // H*W

__device__ inline u16 f2bf(float f) {
  union { float f; uint32_t u; } un; un.f = f;
  uint32_t u = un.u;
  u += 0x7fffu + ((u >> 16) & 1u);
  return (u16)(u >> 16);
}
__device__ inline float bf2f(u16 h) {
  union { uint32_t u; float f; } un; un.u = ((uint32_t)h) << 16; return un.f;
}

__device__ inline void gload_lds16(const u16* g, u16* l) {
  __builtin_amdgcn_global_load_lds((const __attribute__((address_space(1))) void*)g,
                                   (__attribute__((address_space(3))) void*)l, 16, 0, 0);
}

// ---------------------------------------------------------------------------
// LayerNorm: x [B, C, N] -> xn bf16 [B*N, C]
// ---------------------------------------------------------------------------
__global__ __launch_bounds__(256) void ln_kernel(const float* __restrict__ x,
                                                 const float* __restrict__ gamma,
                                                 const float* __restrict__ beta,
                                                 u16* __restrict__ xn) {
  __shared__ float tile[CDIM][33];
  __shared__ float reds[8][32];
  __shared__ float reds2[8][32];
  __shared__ float mu_s[32], rs_s[32];

  int b  = blockIdx.x >> 7;
  int n0 = (blockIdx.x & 127) * 32;
  const float* xb = x + (size_t)b * CDIM * NTOK;

  int t = threadIdx.x & 31;
  int g = threadIdx.x >> 5;

  for (int c = g; c < CDIM; c += 8)
    tile[c][t] = xb[(size_t)c * NTOK + n0 + t];
  __syncthreads();

  float s = 0.f, s2 = 0.f;
  for (int c = g * 32; c < g * 32 + 32; ++c) {
    float v = tile[c][t];
    s += v; s2 += v * v;
  }
  reds[g][t] = s; reds2[g][t] = s2;
  __syncthreads();
  if (threadIdx.x < 32) {
    float ts = 0.f, ts2 = 0.f;
    for (int gg = 0; gg < 8; ++gg) { ts += reds[gg][threadIdx.x]; ts2 += reds2[gg][threadIdx.x]; }
    float mu = ts / CDIM;
    float var = ts2 / CDIM - mu * mu;
    mu_s[threadIdx.x] = mu;
    rs_s[threadIdx.x] = rsqrtf(var + 1e-5f);
  }
  __syncthreads();

  int c = threadIdx.x;
  float gam = gamma[c], bet = beta[c];
  u16* out = xn + ((size_t)b * NTOK + n0) * CDIM;
  for (int tt = 0; tt < 32; ++tt) {
    float v = tile[c][tt];
    float y = (v - mu_s[tt]) * rs_s[tt] * gam + bet;
    out[(size_t)tt * CDIM + c] = f2bf(y);
  }
}

// ---------------------------------------------------------------------------
// W [K, Cout] fp32 -> WT bf16 [Cout, K]
// ---------------------------------------------------------------------------
__global__ __launch_bounds__(256) void wt_kernel(const float* __restrict__ W,
                                                 u16* __restrict__ WT) {
  __shared__ float tile[32][33];
  int i0 = blockIdx.y * 32;
  int j0 = blockIdx.x * 32;
  int tx = threadIdx.x, ty = threadIdx.y;
  for (int r = ty; r < 32; r += 8)
    tile[r][tx] = W[(size_t)(i0 + r) * CDIM + j0 + tx];
  __syncthreads();
  for (int r = ty; r < 32; r += 8)
    WT[(size_t)(j0 + r) * CDIM + i0 + tx] = f2bf(tile[tx][r]);
}

// ---------------------------------------------------------------------------
// bf16 MFMA GEMM (projections): C = A[M,K] * B[Nt,K]^T
// MODE 0: bf16 row-major; MODE 1: bf16 transposed C[n*M+m]
// ---------------------------------------------------------------------------
template <int BM, int BN, int MODE>
__global__ __launch_bounds__(256) void gemm_bt(const u16* __restrict__ Ag,
                                               const u16* __restrict__ Bg,
                                               void* __restrict__ Cg,
                                               int M, int Nt, int K,
                                               size_t sA_, size_t sB_, size_t sC_) {
  constexpr int BK = 32;
  constexpr int TM = BM / 32;
  constexpr int TN = BN / 32;
  __shared__ u16 shA[BM][BK + 8];
  __shared__ u16 shB[BN][BK + 8];

  int bz = blockIdx.z;
  const u16* A = Ag + (size_t)bz * sA_;
  const u16* B = Bg + (size_t)bz * sB_;

  int m0 = blockIdx.y * BM;
  int n0 = blockIdx.x * BN;

  int tid  = threadIdx.x;
  int lane = tid & 63;
  int wave = tid >> 6;
  int wm = wave >> 1, wn = wave & 1;
  int col  = lane & 15;
  int quad = lane >> 4;

  f32x4 acc[TM][TN];
#pragma unroll
  for (int i = 0; i < TM; ++i)
#pragma unroll
    for (int j = 0; j < TN; ++j) acc[i][j] = (f32x4){0.f, 0.f, 0.f, 0.f};

  constexpr int ACH = BM * BK / 8;
  constexpr int BCH = BN * BK / 8;

  for (int kb = 0; kb < K; kb += BK) {
    __syncthreads();
#pragma unroll
    for (int c = tid; c < ACH; c += 256) {
      int row = c >> 2, kc = c & 3;
      *(uint4*)&shA[row][kc * 8] = *(const uint4*)&A[(size_t)(m0 + row) * K + kb + kc * 8];
    }
#pragma unroll
    for (int c = tid; c < BCH; c += 256) {
      int row = c >> 2, kc = c & 3;
      *(uint4*)&shB[row][kc * 8] = *(const uint4*)&B[(size_t)(n0 + row) * K + kb + kc * 8];
    }
    __syncthreads();

    bf16x8 af[TM], bfv[TN];
#pragma unroll
    for (int i = 0; i < TM; ++i)
      af[i] = *(const bf16x8*)&shA[wm * (BM / 2) + i * 16 + col][quad * 8];
#pragma unroll
    for (int j = 0; j < TN; ++j)
      bfv[j] = *(const bf16x8*)&shB[wn * (BN / 2) + j * 16 + col][quad * 8];
#pragma unroll
    for (int i = 0; i < TM; ++i)
#pragma unroll
      for (int j = 0; j < TN; ++j)
        acc[i][j] = __builtin_amdgcn_mfma_f32_16x16x32_bf16(af[i], bfv[j], acc[i][j], 0, 0, 0);
  }

  int r0 = quad * 4;
#pragma unroll
  for (int i = 0; i < TM; ++i) {
    int mbase = m0 + wm * (BM / 2) + i * 16 + r0;
#pragma unroll
    for (int j = 0; j < TN; ++j) {
      int n = n0 + wn * (BN / 2) + j * 16 + col;
#pragma unroll
      for (int r = 0; r < 4; ++r) {
        int m = mbase + r;
        float v = acc[i][j][r];
        if (MODE == 0) {
          ((u16*)Cg)[(size_t)bz * sC_ + (size_t)m * Nt + n] = f2bf(v);
        } else {
          ((u16*)Cg)[(size_t)bz * sC_ + (size_t)n * M + m] = f2bf(v);
        }
      }
    }
  }
}

// ---------------------------------------------------------------------------
// Fused flash attention, wave-owns-rows + async global_load_lds staging.
// Block: 256 thr = 4 waves; wave w owns Q rows [w*16, w*16+16).
// K/V double-buffered in UNPADDED LDS tiles (global_load_lds requires
// lane-contiguous dest); bank conflicts broken by XOR-swizzling the 16B
// chunk column against the row index on the staging (global) side and
// applying the same XOR on the read side.
//   K tile [64][256] u16: pos = chunk ^ (row & 31)
//   V tile [256][64] u16: pos = chunk ^ (row & 7)
// 1 barrier/tile (end-of-tile: drains prefetch vmcnt + buffer handoff).
// P1/P2 per-wave private LDS (padded, no barrier needed).
// ---------------------------------------------------------------------------
#define PLD 72

__global__ __launch_bounds__(256, 1) void fa_kernel(const u16* __restrict__ Qg,
                                                    const u16* __restrict__ Kg,
                                                    const u16* __restrict__ Vtg,
                                                    const u16* __restrict__ xng,
                                                    const float* __restrict__ w1p,
                                                    const float* __restrict__ w2p,
                                                    float* __restrict__ outg) {
  // K0 32768 | K1 32768 | V0 32768 | V1 32768 | P 18432 = 149504 B
  __shared__ __align__(16) char smem[149504];
  u16* Kb0 = (u16*)smem;
  u16* Kb1 = (u16*)(smem + 32768);
  u16* Vb0 = (u16*)(smem + 65536);
  u16* Vb1 = (u16*)(smem + 98304);
  u16* Pb  = (u16*)(smem + 131072);
  float* otile = (float*)smem;          // epilogue overlay [256][68]

  int b  = blockIdx.x & 3;              // XCD swizzle: same XCD -> same batch
  int q0 = (blockIdx.x >> 2) * 64;

  const u16* Q  = Qg  + (size_t)b * NTOK * CDIM;
  const u16* K  = Kg  + (size_t)b * NTOK * CDIM;
  const u16* Vt = Vtg + (size_t)b * NTOK * CDIM;

  int tid  = threadIdx.x;
  int lane = tid & 63;
  int wave = tid >> 6;
  int col = lane & 15, quad = lane >> 4;

  u16* P1 = Pb + wave * 2304;           // per-wave [16][72] u16
  u16* P2 = P1 + 1152;

  // ---- async stage of one KV tile (n1 = kv row offset) ----
  auto stage = [&](int n1, u16* Kdst, u16* Vdst) {
    // K tile: 2048 16B-chunks, rows of 32 chunks, swizzle pos^=(row&31)
#pragma unroll
    for (int it = 0; it < 8; ++it) {
      int c = it * 256 + wave * 64 + lane;
      int row = c >> 5, pos = c & 31;
      int ch = pos ^ (row & 31);
      gload_lds16(K + (size_t)(n1 + row) * CDIM + ch * 8,
                  Kdst + (size_t)(it * 256 + wave * 64) * 8);
    }
    // V tile: 2048 chunks, rows of 8 chunks, swizzle pos^=(row&7)
#pragma unroll
    for (int it = 0; it < 8; ++it) {
      int c = it * 256 + wave * 64 + lane;
      int row = c >> 3, pos = c & 7;
      int ch = pos ^ (row & 7);
      gload_lds16(Vt + (size_t)row * NTOK + n1 + ch * 8,
                  Vdst + (size_t)(it * 256 + wave * 64) * 8);
    }
  };

  stage(0, Kb0, Vb0);

  // ---- Q A-frags straight from global (16B contiguous per frag) ----
  bf16x8 aq[8];
#pragma unroll
  for (int kk = 0; kk < 8; ++kk)
    aq[kk] = *(const bf16x8*)&Q[(size_t)(q0 + wave * 16 + col) * CDIM + kk * 32 + quad * 8];

  f32x4 o1[16], o2[16];
#pragma unroll
  for (int j = 0; j < 16; ++j) {
    o1[j] = (f32x4){0.f, 0.f, 0.f, 0.f};
    o2[j] = (f32x4){0.f, 0.f, 0.f, 0.f};
  }
  float mr[4], lr[4];
#pragma unroll
  for (int r = 0; r < 4; ++r) { mr[r] = -1e30f; lr[r] = 0.f; }

  __syncthreads();   // tile 0 staged (vmcnt drained by barrier semantics)

  for (int t = 0; t < 64; ++t) {
    const u16* Ks = (t & 1) ? Kb1 : Kb0;
    const u16* Vs = (t & 1) ? Vb1 : Vb0;

    // ---- issue async prefetch of tile t+1 into the inactive buffer ----
    if (t < 63)
      stage((t + 1) * 64, (t & 1) ? Kb0 : Kb1, (t & 1) ? Vb0 : Vb1);

    // ---- S = Q K^T : wave computes its 16 rows x 64 cols ----
    f32x4 sacc[4];
#pragma unroll
    for (int j = 0; j < 4; ++j) sacc[j] = (f32x4){0.f, 0.f, 0.f, 0.f};
#pragma unroll
    for (int kk = 0; kk < 8; ++kk) {
#pragma unroll
      for (int j = 0; j < 4; ++j) {
        int kr = j * 16 + col;
        bf16x8 bk = *(const bf16x8*)&Ks[(size_t)kr * 256 + ((kk * 4 + quad) ^ (kr & 31)) * 8];
        sacc[j] = __builtin_amdgcn_mfma_f32_16x16x32_bf16(aq[kk], bk, sacc[j], 0, 0, 0);
      }
    }

    // ---- row stats in registers (rows = quad*4+r, reduce over 16-lane col group) ----
    float pm[4];
#pragma unroll
    for (int r = 0; r < 4; ++r)
      pm[r] = fmaxf(fmaxf(sacc[0][r], sacc[1][r]), fmaxf(sacc[2][r], sacc[3][r]));
#pragma unroll
    for (int off = 1; off < 16; off <<= 1)
#pragma unroll
      for (int r = 0; r < 4; ++r) pm[r] = fmaxf(pm[r], __shfl_xor(pm[r], off));

    float mnew[4], alpha[4], rs[4];
#pragma unroll
    for (int r = 0; r < 4; ++r) {
      mnew[r] = fmaxf(mr[r], pm[r]);
      alpha[r] = __expf(mr[r] - mnew[r]);
      rs[r] = 0.f;
    }

    // ---- P1 = exp(S - m), P2 = relu(S)^2 -> per-wave LDS ----
#pragma unroll
    for (int j = 0; j < 4; ++j)
#pragma unroll
      for (int r = 0; r < 4; ++r) {
        float sv = sacc[j][r];
        float p1 = __expf(sv - mnew[r]);
        rs[r] += p1;
        float p2 = sv > 0.f ? sv * sv : 0.f;
        P1[(size_t)(quad * 4 + r) * PLD + j * 16 + col] = f2bf(p1);
        P2[(size_t)(quad * 4 + r) * PLD + j * 16 + col] = f2bf(p2);
      }
#pragma unroll
    for (int off = 1; off < 16; off <<= 1)
#pragma unroll
      for (int r = 0; r < 4; ++r) rs[r] += __shfl_xor(rs[r], off);
#pragma unroll
    for (int r = 0; r < 4; ++r) {
      lr[r] = lr[r] * alpha[r] + rs[r];
      mr[r] = mnew[r];
    }
    // rescale O1 by alpha
#pragma unroll
    for (int j = 0; j < 16; ++j)
#pragma unroll
      for (int r = 0; r < 4; ++r) o1[j][r] *= alpha[r];

    // ---- O1 += P1 V, O2 += P2 V over all 256 C columns (per-wave, no barrier)
#pragma unroll
    for (int kk = 0; kk < 2; ++kk) {
      bf16x8 pa1 = *(const bf16x8*)&P1[(size_t)col * PLD + kk * 32 + quad * 8];
      bf16x8 pa2 = *(const bf16x8*)&P2[(size_t)col * PLD + kk * 32 + quad * 8];
#pragma unroll
      for (int j = 0; j < 16; ++j) {
        int vr = j * 16 + col;
        bf16x8 bv = *(const bf16x8*)&Vs[(size_t)vr * 64 + ((kk * 4 + quad) ^ (col & 7)) * 8];
        o1[j] = __builtin_amdgcn_mfma_f32_16x16x32_bf16(pa1, bv, o1[j], 0, 0, 0);
        o2[j] = __builtin_amdgcn_mfma_f32_16x16x32_bf16(pa2, bv, o2[j], 0, 0, 0);
      }
    }

    __syncthreads();   // prefetch complete + all waves done with cur buffers
  }

  // ---- epilogue: combine, residual, transpose to [c][n] ----
  float e1 = __expf(w1p[0]), e2 = __expf(w2p[0]);
  float a1 = e1 / (e1 + e2), a2 = e2 / (e1 + e2);
  float linv[4];
#pragma unroll
  for (int r = 0; r < 4; ++r) linv[r] = a1 / lr[r];

#pragma unroll
  for (int j = 0; j < 16; ++j)
#pragma unroll
    for (int r = 0; r < 4; ++r) {
      int row = wave * 16 + quad * 4 + r;   // local n
      int c   = j * 16 + col;
      float v = o1[j][r] * linv[r] + a2 * o2[j][r];
      v += bf2f(xng[((size_t)b * NTOK + q0 + row) * CDIM + c]);
      otile[(size_t)c * 68 + row] = v;
    }
  __syncthreads();

#pragma unroll
  for (int it = 0; it < 16; ++it) {
    int c  = it * 16 + (tid >> 4);
    int ch = tid & 15;
    *(float4*)&outg[((size_t)b * CDIM + c) * NTOK + q0 + ch * 4] =
        *(const float4*)&otile[(size_t)c * 68 + ch * 4];
  }
}

// ---------------------------------------------------------------------------
extern "C" void kernel_launch(void* const* d_in, const int* in_sizes, int n_in,
                              void* d_out, int out_size, void* d_ws, size_t ws_size,
                              hipStream_t stream) {
  const float* x     = (const float*)d_in[0];
  const float* gamma = (const float*)d_in[1];
  const float* beta  = (const float*)d_in[2];
  const float* Wq    = (const float*)d_in[3];
  const float* Wk    = (const float*)d_in[4];
  const float* Wv    = (const float*)d_in[5];
  const float* w1    = (const float*)d_in[6];
  const float* w2    = (const float*)d_in[7];
  float* out = (float*)d_out;

  char* ws = (char*)d_ws;
  size_t off = 0;
  u16* xn  = (u16*)(ws + off); off += (size_t)BATCH * NTOK * CDIM * 2;
  u16* WqT = (u16*)(ws + off); off += (size_t)CDIM * CDIM * 2;
  u16* WkT = (u16*)(ws + off); off += (size_t)CDIM * CDIM * 2;
  u16* WvT = (u16*)(ws + off); off += (size_t)CDIM * CDIM * 2;
  u16* Qb  = (u16*)(ws + off); off += (size_t)BATCH * NTOK * CDIM * 2;
  u16* Kb  = (u16*)(ws + off); off += (size_t)BATCH * NTOK * CDIM * 2;
  u16* VT  = (u16*)(ws + off); off += (size_t)BATCH * NTOK * CDIM * 2;  // [b][c][n]

  // 1) LayerNorm -> xn bf16 [B*N, C]
  ln_kernel<<<dim3(BATCH * (NTOK / 32)), 256, 0, stream>>>(x, gamma, beta, xn);

  // 2) weight transposes
  wt_kernel<<<dim3(8, 8), dim3(32, 8), 0, stream>>>(Wq, WqT);
  wt_kernel<<<dim3(8, 8), dim3(32, 8), 0, stream>>>(Wk, WkT);
  wt_kernel<<<dim3(8, 8), dim3(32, 8), 0, stream>>>(Wv, WvT);

  // 3) projections
  gemm_bt<128, 64, 0><<<dim3(4, 128, 1), 256, 0, stream>>>(
      xn, WqT, Qb, BATCH * NTOK, CDIM, CDIM, 0, 0, 0);
  gemm_bt<128, 64, 0><<<dim3(4, 128, 1), 256, 0, stream>>>(
      xn, WkT, Kb, BATCH * NTOK, CDIM, CDIM, 0, 0, 0);
  gemm_bt<128, 64, 1><<<dim3(4, 32, BATCH), 256, 0, stream>>>(
      xn, WvT, VT, NTOK, CDIM, CDIM,
      (size_t)NTOK * CDIM, 0, (size_t)NTOK * CDIM);

  // 4) fused attention + mix + residual + transpose
  fa_kernel<<<dim3(256), 256, 0, stream>>>(Qb, Kb, VT, xn, w1, w2, out);
}